// Round 8
// baseline (278.275 us; speedup 1.0000x reference)
//
#include <hip/hip_runtime.h>
#include <hip/hip_bf16.h>
#include <stdint.h>

typedef __bf16 bf16x8 __attribute__((ext_vector_type(8)));
typedef __bf16 bf16x4 __attribute__((ext_vector_type(4)));
typedef float  f32x4  __attribute__((ext_vector_type(4)));

#define MFMA16(a, b, c) __builtin_amdgcn_mfma_f32_16x16x32_bf16(a, b, c, 0, 0, 0)

#if __has_builtin(__builtin_amdgcn_exp2f)
#define EXP2(x) __builtin_amdgcn_exp2f(x)
#else
#define EXP2(x) exp2f(x)
#endif

// async 16B global->LDS (dest = wave-uniform base + lane*16)
__device__ __forceinline__ void ld16(void* lds, const void* g) {
    __builtin_amdgcn_global_load_lds(
        (const __attribute__((address_space(1))) void*)(uintptr_t)g,
        (__attribute__((address_space(3))) void*)(uint32_t)(uintptr_t)lds,
        16, 0, 0);
}

// ws layout (bf16 elems), 40 MB total:
// [0,4Mi)     x as bf16 (dead after qkv) -> reused as Y [B,T,C]
// [4Mi,8Mi)   W^T x4 (Wq,Wk,Wv,Wp)
// [8Mi,12Mi)  Q (pre-scaled) / [12Mi,16Mi) K / [16Mi,20Mi) V^T
#define XB_OFF  0
#define WT_OFF  4194304
#define Q_OFF   8388608
#define K_OFF   12582912
#define VT_OFF  16777216
#define Y_OFF   0

// -------- software grid barrier (counters in d_out[0..2], memset to 0) --------
// SAFE BY CONSTRUCTION: 256 blocks x 100864B LDS -> a CU cannot host 2 blocks,
// grid == 256 CUs -> all blocks co-resident -> spin cannot deadlock.
__device__ __forceinline__ void gsync(unsigned* bar) {
    __syncthreads();
    if (threadIdx.x == 0) {
        __threadfence();                    // publish this block's writes
        atomicAdd(bar, 1u);
        while (atomicAdd(bar, 0u) < 256u) { __builtin_amdgcn_s_sleep(8); }
        __threadfence();                    // acquire other blocks' writes
    }
    __syncthreads();
}

// ---- 512-thread GEMM mainloop: C[128x128] += A[128x1024] * BT[128x1024]^T ----
// Round-5 proven structure (BK=32, no swizzle: the 46us qkv config), remapped
// to 8 waves in a 4x2 grid (wave sub-tile 32x64, acc[2][4]).
__device__ __forceinline__ void mainloop512(const __bf16* __restrict__ A,
                                            const __bf16* __restrict__ BT,
                                            __bf16* As, __bf16* Bs,
                                            f32x4 acc[2][4]) {
    const int tid  = threadIdx.x;
    const int lane = tid & 63;
    const int quad = lane >> 4;
    const int l16  = lane & 15;
    const int wid  = tid >> 6;
    const int wm   = wid >> 1;          // 0..3
    const int wn   = wid & 1;           // 0..1
    const int srow = tid >> 2;          // 0..127 (4 lanes per row)
    const int scol = (tid & 3) * 8;

    for (int k0 = 0; k0 < 1024; k0 += 32) {
        ld16(As + tid * 8, A  + (size_t)srow * 1024 + k0 + scol);
        ld16(Bs + tid * 8, BT + (size_t)srow * 1024 + k0 + scol);
        __syncthreads();
        bf16x8 af[2], bf[4];
#pragma unroll
        for (int mt = 0; mt < 2; mt++)
            af[mt] = *(const bf16x8*)(As + (wm * 32 + mt * 16 + l16) * 32 + quad * 8);
#pragma unroll
        for (int nt = 0; nt < 4; nt++)
            bf[nt] = *(const bf16x8*)(Bs + (wn * 64 + nt * 16 + l16) * 32 + quad * 8);
#pragma unroll
        for (int mt = 0; mt < 2; mt++)
#pragma unroll
            for (int nt = 0; nt < 4; nt++)
                acc[mt][nt] = MFMA16(af[mt], bf[nt], acc[mt][nt]);
        __syncthreads();
    }
}

// ================= fused persistent kernel: prep -> qkv -> attn -> proj ========
// Round 8: round-5 kernels (best measured config, 177us) fused into ONE launch;
// ~12-15us/launch gap x 3 saved. Stages separated by gsync. Grid 256 x 512.
__global__ __launch_bounds__(512, 1) void mega_kernel(
        const float* __restrict__ x,
        const float* __restrict__ Wq, const float* __restrict__ bq,
        const float* __restrict__ Wk, const float* __restrict__ bk,
        const float* __restrict__ Wv, const float* __restrict__ bv,
        const float* __restrict__ Wp, const float* __restrict__ bp,
        __bf16* ws, float* out, unsigned* bar) {
    __shared__ __attribute__((aligned(16))) char smem[100864];

    const int tid  = threadIdx.x;
    const int lane = tid & 63;
    const int wid  = tid >> 6;
    const int quad = lane >> 4;
    const int l16  = lane & 15;
    const int bkid = blockIdx.x;
    const f32x4 zz = {0.f, 0.f, 0.f, 0.f};

    // ---------------- stage 1: x f32->bf16 + W transpose x4 --------------------
    {
        __bf16* xb = ws + XB_OFF;
        const int gtid = bkid * 512 + tid;
#pragma unroll
        for (int j = 0; j < 8; j++) {
            int i = (gtid + j * 131072) * 4;
            float4 v = *(const float4*)(x + i);
            xb[i]     = (__bf16)v.x;
            xb[i + 1] = (__bf16)v.y;
            xb[i + 2] = (__bf16)v.z;
            xb[i + 3] = (__bf16)v.w;
        }
        __bf16 (*t)[33] = (__bf16(*)[33])smem;
        const int tx = tid & 31, ty = tid >> 5;          // 32 x 16
        for (int tt = 0; tt < 16; tt++) {
            const int tile = bkid * 16 + tt;
            const int z = tile >> 10, rem = tile & 1023;
            const int by = rem >> 5, bx = rem & 31;
            const float* W = (z == 0) ? Wq : (z == 1) ? Wk : (z == 2) ? Wv : Wp;
            __bf16* D = ws + WT_OFF + (size_t)z * 1048576;
            t[ty][tx]      = (__bf16)W[(size_t)(by * 32 + ty) * 1024 + bx * 32 + tx];
            t[ty + 16][tx] = (__bf16)W[(size_t)(by * 32 + ty + 16) * 1024 + bx * 32 + tx];
            __syncthreads();
            D[(size_t)(bx * 32 + ty) * 1024 + by * 32 + tx]      = t[tx][ty];
            D[(size_t)(bx * 32 + ty + 16) * 1024 + by * 32 + tx] = t[tx][ty + 16];
            __syncthreads();
        }
    }
    gsync(&bar[0]);

    // ---------------- stage 2: QKV projection (3 x 128^2 tiles per block) ------
    // XCD super-tiling preserved from round 3 (FETCH 68.7 -> 20.5 MB verified):
    // XCD g owns 8-m-row band x 12 (n,z) cols; m fastest.
    {
        __bf16* As = (__bf16*)smem;
        __bf16* Bs = As + 4096;
        const int g = bkid & 7, r0 = bkid >> 3;
        const int wm = wid >> 1, wn = wid & 1;
        for (int t3 = 0; t3 < 3; t3++) {
            const int r  = r0 + t3 * 32;              // 0..95
            const int mB = ((g >> 1) << 3) + (r & 7);
            const int nz = (g & 1) * 12 + (r >> 3);
            const int z  = nz >> 3;
            const int n  = nz & 7;
            const int m0 = mB * 128, n0 = n * 128;
            const __bf16* BT  = ws + WT_OFF + (size_t)z * 1048576;
            const float* bias = (z == 0) ? bq : (z == 1) ? bk : bv;
            f32x4 acc[2][4];
#pragma unroll
            for (int i = 0; i < 2; i++)
#pragma unroll
                for (int j = 0; j < 4; j++) acc[i][j] = zz;
            mainloop512(ws + XB_OFF + (size_t)m0 * 1024, BT + (size_t)n0 * 1024,
                        As, Bs, acc);
            if (z == 2) {
                // V^T: vt[((b*16+h)*64+hd)*2048 + t], 4 consecutive t packed
                __bf16* vt = ws + VT_OFF;
#pragma unroll
                for (int nt = 0; nt < 4; nt++) {
                    int col = n0 + wn * 64 + nt * 16 + l16;
                    float bv = bias[col];
                    int h = col >> 6, hd = col & 63;
#pragma unroll
                    for (int mt = 0; mt < 2; mt++) {
                        int m = m0 + wm * 32 + mt * 16 + quad * 4;
                        int b = m >> 11, tt = m & 2047;
                        bf16x4 pk;
                        pk.x = (__bf16)(acc[mt][nt].x + bv);
                        pk.y = (__bf16)(acc[mt][nt].y + bv);
                        pk.z = (__bf16)(acc[mt][nt].z + bv);
                        pk.w = (__bf16)(acc[mt][nt].w + bv);
                        *(bf16x4*)(vt + ((size_t)((b * 16 + h) * 64 + hd)) * 2048 + tt) = pk;
                    }
                }
            } else {
                // Q (z=0, pre-scaled by (1/8)*log2(e)) / K (z=1): [B,H,T,HD]
                const float sq = (z == 0) ? 0.18033688011112042f : 1.0f;
                __bf16* dst = ws + Q_OFF + (size_t)z * 4194304;
#pragma unroll
                for (int nt = 0; nt < 4; nt++) {
                    int col = n0 + wn * 64 + nt * 16 + l16;
                    float bv = bias[col];
                    int h = col >> 6, hd = col & 63;
#pragma unroll
                    for (int mt = 0; mt < 2; mt++) {
#pragma unroll
                        for (int r4 = 0; r4 < 4; r4++) {
                            int m = m0 + wm * 32 + mt * 16 + quad * 4 + r4;
                            int b = m >> 11, tt = m & 2047;
                            float v = (acc[mt][nt][r4] + bv) * sq;
                            dst[((size_t)((b * 16 + h) * 2048 + tt)) * 64 + hd] = (__bf16)v;
                        }
                    }
                }
            }
        }
    }
    gsync(&bar[1]);

    // ---------------- stage 3: flash attention (round-5 v8, verbatim) ----------
    {
        __bf16 (*Kb)[128 * 64] = (__bf16(*)[128 * 64])(smem);
        __bf16 (*Vb)[64 * 128] = (__bf16(*)[64 * 128])(smem + 32768);
        __bf16 (*Ps)[16 * 136] = (__bf16(*)[16 * 136])(smem + 65536);
        float  (*Lw)[16]       = (float(*)[16])(smem + 100352);
        const __bf16* Qg  = ws + Q_OFF;
        const __bf16* Kg  = ws + K_OFF;
        const __bf16* Vtg = ws + VT_OFF;
        __bf16* Y = ws + Y_OFF;

        const int head  = ((bkid & 7) << 2) + ((bkid >> 3) & 3);  // 4 heads/XCD
        const int ipair = bkid >> 5;                              // 0..7
        const size_t hbase = (size_t)head * (2048 * 64);

        const int kr  = lane >> 3;            // K row-in-chunk (= row&7)
        const int kc8 = (lane & 7) ^ kr;      // K swizzled 16B slot
        const int vr  = lane >> 4;            // V row-in-chunk
        const int vl  = lane & 15;

#pragma unroll 1
        for (int itm = 0; itm < 2; itm++) {
            const int qi  = itm ? (15 - ipair) : ipair;
            const int ktl = qi;
            const int q0  = qi << 7;
            const int q0w = q0 + wid * 16;

            bf16x8 qf[2];
#pragma unroll
            for (int kk = 0; kk < 2; kk++)
                qf[kk] = *(const bf16x8*)(Qg + hbase +
                                          (size_t)(q0w + l16) * 64 + kk * 32 + quad * 8);

            f32x4 acc_o[4];
#pragma unroll
            for (int jj = 0; jj < 4; jj++) acc_o[jj] = zz;
            float l_s = 0.f;

            auto stage = [&](int bf, int key0) {
#pragma unroll
                for (int i = 0; i < 2; i++) {
                    const int c = wid * 2 + i;
                    ld16((char*)&Kb[bf][0] + c * 1024 + lane * 16,
                         Kg + hbase + (size_t)(key0 + c * 8 + kr) * 64 + kc8 * 8);
                }
#pragma unroll
                for (int i = 0; i < 2; i++) {
                    const int c = wid * 2 + i;
                    const int row = c * 4 + vr;
                    const int vc  = vl ^ (row & 7);
                    ld16((char*)&Vb[bf][0] + c * 1024 + lane * 16,
                         Vtg + hbase + (size_t)row * 2048 + key0 + vc * 8);
                }
            };

            stage(0, 0);
            __syncthreads();
            int buf = 0;

#pragma unroll 1
            for (int kt = 0; kt <= ktl; kt++) {
                if (kt < ktl) stage(buf ^ 1, (kt + 1) << 7);

                f32x4 accs[8];
#pragma unroll
                for (int mt = 0; mt < 8; mt++) accs[mt] = zz;
#pragma unroll
                for (int kk = 0; kk < 2; kk++) {
#pragma unroll
                    for (int mt = 0; mt < 8; mt++) {
                        bf16x8 kf = *(const bf16x8*)(&Kb[buf][(mt * 16 + l16) * 64 +
                                                     (((kk * 4 + quad) ^ (l16 & 7)) << 3)]);
                        accs[mt] = MFMA16(kf, qf[kk], accs[mt]);
                    }
                }

                if (kt == ktl) {
#pragma unroll
                    for (int mt = 0; mt < 8; mt++) {
                        int q_g = wid * 16 + l16;
#pragma unroll
                        for (int r4 = 0; r4 < 4; r4++) {
                            int key_g = mt * 16 + quad * 4 + r4;
                            if (key_g > q_g) accs[mt][r4] = -1e30f;
                        }
                    }
                }

                float s_s = 0.f;
#pragma unroll
                for (int mt = 0; mt < 8; mt++) {
                    f32x4 pv;
                    pv.x = EXP2(accs[mt].x);
                    pv.y = EXP2(accs[mt].y);
                    pv.z = EXP2(accs[mt].z);
                    pv.w = EXP2(accs[mt].w);
                    s_s += (pv.x + pv.y) + (pv.z + pv.w);
                    bf16x4 pk;
                    pk.x = (__bf16)pv.x; pk.y = (__bf16)pv.y;
                    pk.z = (__bf16)pv.z; pk.w = (__bf16)pv.w;
                    *(bf16x4*)(&Ps[wid][l16 * 136 + mt * 16 + quad * 4]) = pk;
                }
                {
                    float t = s_s;
                    t += __shfl_xor(t, 16);
                    t += __shfl_xor(t, 32);
                    l_s += t;
                }

#pragma unroll
                for (int kk = 0; kk < 4; kk++) {
                    bf16x8 pf, vf[4];
                    pf = *(const bf16x8*)(&Ps[wid][l16 * 136 + kk * 32 + quad * 8]);
#pragma unroll
                    for (int nv = 0; nv < 4; nv++)
                        vf[nv] = *(const bf16x8*)(&Vb[buf][(nv * 16 + l16) * 128 +
                                                  (((kk * 4 + quad) ^ (l16 & 7)) << 3)]);
#pragma unroll
                    for (int nv = 0; nv < 4; nv++)
                        acc_o[nv] = MFMA16(pf, vf[nv], acc_o[nv]);
                }

                __syncthreads();
                buf ^= 1;
            }

            if (quad == 0) Lw[wid][l16] = l_s;
            float* Om = (float*)&Ps[wid][0];
#pragma unroll
            for (int nv = 0; nv < 4; nv++)
#pragma unroll
                for (int r4 = 0; r4 < 4; r4++)
                    Om[(quad * 4 + r4) * 68 + nv * 16 + l16] = acc_o[nv][r4];
            __syncthreads();

            {
                const int q  = lane >> 2;
                const int d0 = (lane & 3) * 16;
                float li = 1.0f / Lw[wid][q];
                f32x4 s0 = *(const f32x4*)(&Om[q * 68 + d0]);
                f32x4 s1 = *(const f32x4*)(&Om[q * 68 + d0 + 4]);
                f32x4 s2 = *(const f32x4*)(&Om[q * 68 + d0 + 8]);
                f32x4 s3 = *(const f32x4*)(&Om[q * 68 + d0 + 12]);
                bf16x8 o0, o1;
                o0[0] = (__bf16)(s0.x * li); o0[1] = (__bf16)(s0.y * li);
                o0[2] = (__bf16)(s0.z * li); o0[3] = (__bf16)(s0.w * li);
                o0[4] = (__bf16)(s1.x * li); o0[5] = (__bf16)(s1.y * li);
                o0[6] = (__bf16)(s1.z * li); o0[7] = (__bf16)(s1.w * li);
                o1[0] = (__bf16)(s2.x * li); o1[1] = (__bf16)(s2.y * li);
                o1[2] = (__bf16)(s2.z * li); o1[3] = (__bf16)(s2.w * li);
                o1[4] = (__bf16)(s3.x * li); o1[5] = (__bf16)(s3.y * li);
                o1[6] = (__bf16)(s3.z * li); o1[7] = (__bf16)(s3.w * li);
                const int bb = head >> 4, hh = head & 15;
                __bf16* yp = Y + ((size_t)(bb * 2048 + q0w + q)) * 1024 + hh * 64 + d0;
                *(bf16x8*)(yp)     = o0;
                *(bf16x8*)(yp + 8) = o1;
            }
            __syncthreads();
        }
    }
    gsync(&bar[2]);

    // ---------------- stage 4: output projection (1 x 128^2 tile per block) ----
    {
        __bf16* As = (__bf16*)smem;
        __bf16* Bs = As + 4096;
        const int g = bkid & 7, r = bkid >> 3;
        const int m0 = (g * 4 + (r & 3)) * 128;
        const int n0 = (r >> 2) * 128;
        const int wm = wid >> 1, wn = wid & 1;
        f32x4 acc[2][4];
#pragma unroll
        for (int i = 0; i < 2; i++)
#pragma unroll
            for (int j = 0; j < 4; j++) acc[i][j] = zz;
        mainloop512(ws + Y_OFF + (size_t)m0 * 1024,
                    ws + WT_OFF + (size_t)3 * 1048576 + (size_t)n0 * 1024,
                    As, Bs, acc);
#pragma unroll
        for (int nt = 0; nt < 4; nt++) {
            int col = n0 + wn * 64 + nt * 16 + l16;
            float bv = bp[col];
#pragma unroll
            for (int mt = 0; mt < 2; mt++) {
#pragma unroll
                for (int r4 = 0; r4 < 4; r4++) {
                    int m = m0 + wm * 32 + mt * 16 + quad * 4 + r4;
                    out[(size_t)m * 1024 + col] = acc[mt][nt][r4] + bv;
                }
            }
        }
    }
}

extern "C" void kernel_launch(void* const* d_in, const int* in_sizes, int n_in,
                              void* d_out, int out_size, void* d_ws, size_t ws_size,
                              hipStream_t stream) {
    const float* x  = (const float*)d_in[0];
    const float* Wq = (const float*)d_in[1];
    const float* bq = (const float*)d_in[2];
    const float* Wk = (const float*)d_in[3];
    const float* bk = (const float*)d_in[4];
    const float* Wv = (const float*)d_in[5];
    const float* bv = (const float*)d_in[6];
    const float* Wp = (const float*)d_in[7];
    const float* bp = (const float*)d_in[8];
    __bf16* ws  = (__bf16*)d_ws;
    float*  out = (float*)d_out;
    if (ws_size < (size_t)41943040) return;  // need 40 MB scratch

    // barrier counters live in out[0..2]: zeroed here, overwritten only by
    // stage 4 (after the last gsync use). Both ops are graph-capture-safe.
    hipMemsetAsync(d_out, 0, 16, stream);
    mega_kernel<<<dim3(256), dim3(512), 0, stream>>>(
        x, Wq, bq, Wk, bk, Wv, bv, Wp, bp, ws, out, (unsigned*)d_out);
}

// Round 9
// 176.637 us; speedup vs baseline: 1.5754x; 1.5754x over previous
//
#include <hip/hip_runtime.h>
#include <hip/hip_bf16.h>
#include <stdint.h>

typedef __bf16 bf16x8 __attribute__((ext_vector_type(8)));
typedef __bf16 bf16x4 __attribute__((ext_vector_type(4)));
typedef float  f32x4  __attribute__((ext_vector_type(4)));

#define MFMA16(a, b, c) __builtin_amdgcn_mfma_f32_16x16x32_bf16(a, b, c, 0, 0, 0)

#if __has_builtin(__builtin_amdgcn_exp2f)
#define EXP2(x) __builtin_amdgcn_exp2f(x)
#else
#define EXP2(x) exp2f(x)
#endif

// async 16B global->LDS (dest = wave-uniform base + lane*16)
__device__ __forceinline__ void ld16(void* lds, const void* g) {
    __builtin_amdgcn_global_load_lds(
        (const __attribute__((address_space(1))) void*)(uintptr_t)g,
        (__attribute__((address_space(3))) void*)(uint32_t)(uintptr_t)lds,
        16, 0, 0);
}

// ---------------- fused prep: weight transpose x4 + x f32->bf16 ----------------
__global__ __launch_bounds__(1024) void prep_kernel(const float* __restrict__ x,
                                                    const float* __restrict__ W0,
                                                    const float* __restrict__ W1,
                                                    const float* __restrict__ W2,
                                                    const float* __restrict__ W3,
                                                    __bf16* __restrict__ wdst,
                                                    __bf16* __restrict__ xdst) {
    __shared__ __bf16 t[32][33];
    const int z = blockIdx.z;
    const int tx = threadIdx.x, ty = threadIdx.y;
    if (z == 4) {
        int blin = blockIdx.y * 32 + blockIdx.x;
        int i = (blin * 1024 + ty * 32 + tx) * 4;
        float4 v = *(const float4*)(x + i);
        xdst[i]     = (__bf16)v.x;
        xdst[i + 1] = (__bf16)v.y;
        xdst[i + 2] = (__bf16)v.z;
        xdst[i + 3] = (__bf16)v.w;
        return;
    }
    const float* W = (z == 0) ? W0 : (z == 1) ? W1 : (z == 2) ? W2 : W3;
    __bf16* D = wdst + (size_t)z * 1048576;
    t[ty][tx] = (__bf16)W[(size_t)(blockIdx.y * 32 + ty) * 1024 + blockIdx.x * 32 + tx];
    __syncthreads();
    D[(size_t)(blockIdx.x * 32 + ty) * 1024 + blockIdx.y * 32 + tx] = t[tx][ty];
}

// ---------------- shared GEMM mainloop: C[128x128] += A[128xK] * BT[128xK]^T ----
// Round-5 proven form (BK=32, no swizzle): 46.4us qkv, best measured. Rounds
// 6/7 established: BK=64 halves occupancy (net loss); 4-chunk swizzle at 64B
// stride cannot fix the bank pattern (conflict counter unchanged). Leave as is.
__device__ __forceinline__ void gemm_mainloop(const __bf16* __restrict__ A,
                                              const __bf16* __restrict__ BT,
                                              int K, __bf16* As, __bf16* Bs,
                                              f32x4 acc[4][4]) {
    const int tid  = threadIdx.x;
    const int lane = tid & 63;
    const int wid  = tid >> 6;
    const int quad = lane >> 4;
    const int l16  = lane & 15;
    const int wm   = wid >> 1;
    const int wn   = wid & 1;

    const int srow = wid * 16 + (lane >> 2);
    const int scol = (lane & 3) * 8;
    const int sdst = wid * 512 + lane * 8;

    for (int k0 = 0; k0 < K; k0 += 32) {
        ld16(As + sdst,        A  + (size_t)srow        * K + k0 + scol);
        ld16(As + 2048 + sdst, A  + (size_t)(srow + 64) * K + k0 + scol);
        ld16(Bs + sdst,        BT + (size_t)srow        * K + k0 + scol);
        ld16(Bs + 2048 + sdst, BT + (size_t)(srow + 64) * K + k0 + scol);
        __syncthreads();
        bf16x8 af[4], bf[4];
#pragma unroll
        for (int mt = 0; mt < 4; mt++)
            af[mt] = *(const bf16x8*)(As + (wm * 64 + mt * 16 + l16) * 32 + quad * 8);
#pragma unroll
        for (int nt = 0; nt < 4; nt++)
            bf[nt] = *(const bf16x8*)(Bs + (wn * 64 + nt * 16 + l16) * 32 + quad * 8);
#pragma unroll
        for (int mt = 0; mt < 4; mt++)
#pragma unroll
            for (int nt = 0; nt < 4; nt++)
                acc[mt][nt] = MFMA16(af[mt], bf[nt], acc[mt][nt]);
        __syncthreads();
    }
}

// ---- proj mainloop: C[64x128] += A[64xK] * BT[128xK]^T (2 blocks/CU) ----------
// Round 9: proj was 1 block/CU (grid 256) -> zero cross-block latency hiding
// -> 430 TF vs qkv's 560 at 3 blocks/CU. 64-row tiles double the grid to 512
// (12KB LDS -> 2 blocks/CU); same loop structure otherwise.
__device__ __forceinline__ void mainloop64(const __bf16* __restrict__ A,
                                           const __bf16* __restrict__ BT,
                                           int K, __bf16* As, __bf16* Bs,
                                           f32x4 acc[2][4]) {
    const int tid  = threadIdx.x;
    const int lane = tid & 63;
    const int quad = lane >> 4;
    const int l16  = lane & 15;
    const int wid  = tid >> 6;
    const int wm   = wid >> 1;          // 0..1: 32-row half
    const int wn   = wid & 1;           // 0..1: 64-col half
    const int srow = tid >> 2;          // 0..63
    const int scol = (tid & 3) * 8;

    for (int k0 = 0; k0 < K; k0 += 32) {
        ld16(As + tid * 8,        A  + (size_t)srow        * K + k0 + scol);
        ld16(Bs + tid * 8,        BT + (size_t)srow        * K + k0 + scol);
        ld16(Bs + 2048 + tid * 8, BT + (size_t)(srow + 64) * K + k0 + scol);
        __syncthreads();
        bf16x8 af[2], bf[4];
#pragma unroll
        for (int mt = 0; mt < 2; mt++)
            af[mt] = *(const bf16x8*)(As + (wm * 32 + mt * 16 + l16) * 32 + quad * 8);
#pragma unroll
        for (int nt = 0; nt < 4; nt++)
            bf[nt] = *(const bf16x8*)(Bs + (wn * 64 + nt * 16 + l16) * 32 + quad * 8);
#pragma unroll
        for (int mt = 0; mt < 2; mt++)
#pragma unroll
            for (int nt = 0; nt < 4; nt++)
                acc[mt][nt] = MFMA16(af[mt], bf[nt], acc[mt][nt]);
        __syncthreads();
    }
}

// ---------------- QKV projection: X @ W{q,k,v} + b ------------------------------
// XCD super-tiling (round 3, verified: FETCH 68.7 -> 20.5 MB).
// z=0 -> Q [B,H,T,HD] PRE-SCALED by (1/8)*log2(e), z=1 -> K, z=2 -> V^T
__global__ __launch_bounds__(256) void qkv_gemm(const __bf16* __restrict__ X,
                                                const __bf16* __restrict__ WTb,
                                                const float* __restrict__ b0,
                                                const float* __restrict__ b1,
                                                const float* __restrict__ b2,
                                                __bf16* __restrict__ qk,
                                                __bf16* __restrict__ vt) {
    __shared__ __attribute__((aligned(16))) __bf16 As[4096];
    __shared__ __attribute__((aligned(16))) __bf16 Bs[4096];
    const int o  = blockIdx.x;
    const int g  = o & 7, r = o >> 3;
    const int mB = ((g >> 1) << 3) + (r & 7);     // m-tile 0..31
    const int nz = (g & 1) * 12 + (r >> 3);       // 0..23
    const int z  = nz >> 3;                       // 0..2
    const int n  = nz & 7;                        // 0..7
    const __bf16* BT   = WTb + (size_t)z * 1048576;
    const float* bias  = (z == 0) ? b0 : (z == 1) ? b1 : b2;
    const int m0 = mB * 128, n0 = n * 128;
    f32x4 acc[4][4];
    const f32x4 zz = {0.f, 0.f, 0.f, 0.f};
#pragma unroll
    for (int i = 0; i < 4; i++)
#pragma unroll
        for (int j = 0; j < 4; j++) acc[i][j] = zz;
    gemm_mainloop(X + (size_t)m0 * 1024, BT + (size_t)n0 * 1024, 1024, As, Bs, acc);

    const int lane = threadIdx.x & 63, wid = threadIdx.x >> 6;
    const int quad = lane >> 4, l16 = lane & 15, wm = wid >> 1, wn = wid & 1;
    if (z == 2) {
        // V^T epilogue: vt[((b*16+h)*64+hd)*2048 + t], 4 consecutive t packed
#pragma unroll
        for (int nt = 0; nt < 4; nt++) {
            int col = n0 + wn * 64 + nt * 16 + l16;
            float bv = bias[col];
            int h = col >> 6, hd = col & 63;
#pragma unroll
            for (int mt = 0; mt < 4; mt++) {
                int m = m0 + wm * 64 + mt * 16 + quad * 4;
                int b = m >> 11, tt = m & 2047;
                bf16x4 pk;
                pk.x = (__bf16)(acc[mt][nt].x + bv);
                pk.y = (__bf16)(acc[mt][nt].y + bv);
                pk.z = (__bf16)(acc[mt][nt].z + bv);
                pk.w = (__bf16)(acc[mt][nt].w + bv);
                *(bf16x4*)(vt + ((size_t)((b * 16 + h) * 64 + hd)) * 2048 + tt) = pk;
            }
        }
    } else {
        // softmax scale (1/sqrt(64))*log2(e) folded into Q here (z==0)
        const float sq = (z == 0) ? 0.18033688011112042f : 1.0f;
        __bf16* dst = qk + (size_t)z * 4194304;
#pragma unroll
        for (int nt = 0; nt < 4; nt++) {
            int col = n0 + wn * 64 + nt * 16 + l16;
            float bv = bias[col];
            int h = col >> 6, hd = col & 63;
#pragma unroll
            for (int mt = 0; mt < 4; mt++) {
#pragma unroll
                for (int r4 = 0; r4 < 4; r4++) {
                    int m = m0 + wm * 64 + mt * 16 + quad * 4 + r4;
                    int b = m >> 11, tt = m & 2047;
                    float v = (acc[mt][nt][r4] + bv) * sq;
                    dst[((size_t)((b * 16 + h) * 2048 + tt)) * 64 + hd] = (__bf16)v;
                }
            }
        }
    }
}

// ---------------- output projection: Y @ Wp + bp -> out [B,T,C] f32 ------------
// Round 9: 512 blocks x 64x128 tiles (2 blocks/CU). XCD supertile: XCD g owns
// m-tiles g*8..g*8+7 (rows [g*512,(g+1)*512), A 1MB + B 2MB L2-resident),
// r&7 walks m fastest.
__global__ __launch_bounds__(256) void proj_gemm(const __bf16* __restrict__ Yw,
                                                 const __bf16* __restrict__ WT,
                                                 const float* __restrict__ bias,
                                                 float* __restrict__ out) {
    __shared__ __attribute__((aligned(16))) __bf16 As[2048];
    __shared__ __attribute__((aligned(16))) __bf16 Bs[4096];
    const int o = blockIdx.x;
    const int g = o & 7, r = o >> 3;
    const int m0 = (g * 8 + (r & 7)) * 64;
    const int n0 = (r >> 3) * 128;
    f32x4 acc[2][4];
    const f32x4 zz = {0.f, 0.f, 0.f, 0.f};
#pragma unroll
    for (int i = 0; i < 2; i++)
#pragma unroll
        for (int j = 0; j < 4; j++) acc[i][j] = zz;
    mainloop64(Yw + (size_t)m0 * 1024, WT + (size_t)n0 * 1024, 1024, As, Bs, acc);

    const int lane = threadIdx.x & 63, wid = threadIdx.x >> 6;
    const int quad = lane >> 4, l16 = lane & 15, wm = wid >> 1, wn = wid & 1;
#pragma unroll
    for (int nt = 0; nt < 4; nt++) {
        int col = n0 + wn * 64 + nt * 16 + l16;
        float bv = bias[col];
#pragma unroll
        for (int mt = 0; mt < 2; mt++) {
#pragma unroll
            for (int r4 = 0; r4 < 4; r4++) {
                int m = m0 + wm * 32 + mt * 16 + quad * 4 + r4;
                out[(size_t)m * 1024 + col] = acc[mt][nt][r4] + bv;
            }
        }
    }
}

// ---------------- flash attention v8: 8 waves x 16 q-rows (round-5, verbatim) ---
__global__ __launch_bounds__(512, 1) void attn_kernel(const __bf16* __restrict__ Qg,
                                                      const __bf16* __restrict__ Kg,
                                                      const __bf16* __restrict__ Vtg,
                                                      __bf16* __restrict__ Y) {
    __shared__ __attribute__((aligned(16))) __bf16 Kb[2][128 * 64];  // [key][d] swz
    __shared__ __attribute__((aligned(16))) __bf16 Vb[2][64 * 128];  // [d][key] swz
    __shared__ __attribute__((aligned(16))) __bf16 Ps[8][16 * 136];  // per-wave P
    __shared__ __attribute__((aligned(16))) float  Lw[8][16];        // per-wave l

    const int tid  = threadIdx.x;
    const int lane = tid & 63;
    const int wid  = tid >> 6;          // 0..7
    const int quad = lane >> 4;
    const int l16  = lane & 15;
    const int bkid = blockIdx.x;
    const int head  = ((bkid & 7) << 2) + ((bkid >> 3) & 3);  // 4 heads per XCD
    const int ipair = bkid >> 5;                              // 0..7
    const size_t hbase = (size_t)head * (2048 * 64);
    const f32x4 zz = {0.f, 0.f, 0.f, 0.f};

    const int kr  = lane >> 3;            // K row-in-chunk (= row&7)
    const int kc8 = (lane & 7) ^ kr;      // K swizzled 16B slot
    const int vr  = lane >> 4;            // V row-in-chunk
    const int vl  = lane & 15;

#pragma unroll 1
    for (int itm = 0; itm < 2; itm++) {
        const int qi  = itm ? (15 - ipair) : ipair;  // q-tile index == last key tile
        const int ktl = qi;
        const int q0  = qi << 7;
        const int q0w = q0 + wid * 16;               // this wave's 16 q rows

        bf16x8 qf[2];
#pragma unroll
        for (int kk = 0; kk < 2; kk++)
            qf[kk] = *(const bf16x8*)(Qg + hbase +
                                      (size_t)(q0w + l16) * 64 + kk * 32 + quad * 8);

        f32x4 acc_o[4];
#pragma unroll
        for (int jj = 0; jj < 4; jj++) acc_o[jj] = zz;
        float l_s = 0.f;

        auto stage = [&](int bf, int key0) {
#pragma unroll
            for (int i = 0; i < 2; i++) {
                const int c = wid * 2 + i;
                ld16((char*)&Kb[bf][0] + c * 1024 + lane * 16,
                     Kg + hbase + (size_t)(key0 + c * 8 + kr) * 64 + kc8 * 8);
            }
#pragma unroll
            for (int i = 0; i < 2; i++) {
                const int c = wid * 2 + i;
                const int row = c * 4 + vr;
                const int vc  = vl ^ (row & 7);
                ld16((char*)&Vb[bf][0] + c * 1024 + lane * 16,
                     Vtg + hbase + (size_t)row * 2048 + key0 + vc * 8);
            }
        };

        stage(0, 0);
        __syncthreads();
        int buf = 0;

#pragma unroll 1
        for (int kt = 0; kt <= ktl; kt++) {
            if (kt < ktl) stage(buf ^ 1, (kt + 1) << 7);

            f32x4 accs[8];
#pragma unroll
            for (int mt = 0; mt < 8; mt++) accs[mt] = zz;
#pragma unroll
            for (int kk = 0; kk < 2; kk++) {
#pragma unroll
                for (int mt = 0; mt < 8; mt++) {
                    bf16x8 kf = *(const bf16x8*)(&Kb[buf][(mt * 16 + l16) * 64 +
                                                 (((kk * 4 + quad) ^ (l16 & 7)) << 3)]);
                    accs[mt] = MFMA16(kf, qf[kk], accs[mt]);
                }
            }

            if (kt == ktl) {
#pragma unroll
                for (int mt = 0; mt < 8; mt++) {
                    int q_g = wid * 16 + l16;
#pragma unroll
                    for (int r4 = 0; r4 < 4; r4++) {
                        int key_g = mt * 16 + quad * 4 + r4;
                        if (key_g > q_g) accs[mt][r4] = -1e30f;
                    }
                }
            }

            float s_s = 0.f;
#pragma unroll
            for (int mt = 0; mt < 8; mt++) {
                f32x4 pv;
                pv.x = EXP2(accs[mt].x);
                pv.y = EXP2(accs[mt].y);
                pv.z = EXP2(accs[mt].z);
                pv.w = EXP2(accs[mt].w);
                s_s += (pv.x + pv.y) + (pv.z + pv.w);
                bf16x4 pk;
                pk.x = (__bf16)pv.x; pk.y = (__bf16)pv.y;
                pk.z = (__bf16)pv.z; pk.w = (__bf16)pv.w;
                *(bf16x4*)(&Ps[wid][l16 * 136 + mt * 16 + quad * 4]) = pk;
            }
            {
                float t = s_s;
                t += __shfl_xor(t, 16);
                t += __shfl_xor(t, 32);
                l_s += t;
            }

#pragma unroll
            for (int kk = 0; kk < 4; kk++) {
                bf16x8 pf, vf[4];
                pf = *(const bf16x8*)(&Ps[wid][l16 * 136 + kk * 32 + quad * 8]);
#pragma unroll
                for (int nv = 0; nv < 4; nv++)
                    vf[nv] = *(const bf16x8*)(&Vb[buf][(nv * 16 + l16) * 128 +
                                              (((kk * 4 + quad) ^ (l16 & 7)) << 3)]);
#pragma unroll
                for (int nv = 0; nv < 4; nv++)
                    acc_o[nv] = MFMA16(pf, vf[nv], acc_o[nv]);
            }

            __syncthreads();
            buf ^= 1;
        }

        if (quad == 0) Lw[wid][l16] = l_s;
        float* Om = (float*)&Ps[wid][0];
#pragma unroll
        for (int nv = 0; nv < 4; nv++)
#pragma unroll
            for (int r4 = 0; r4 < 4; r4++)
                Om[(quad * 4 + r4) * 68 + nv * 16 + l16] = acc_o[nv][r4];
        __syncthreads();

        {
            const int q  = lane >> 2;          // 0..15
            const int d0 = (lane & 3) * 16;    // 0,16,32,48
            float li = 1.0f / Lw[wid][q];
            f32x4 s0 = *(const f32x4*)(&Om[q * 68 + d0]);
            f32x4 s1 = *(const f32x4*)(&Om[q * 68 + d0 + 4]);
            f32x4 s2 = *(const f32x4*)(&Om[q * 68 + d0 + 8]);
            f32x4 s3 = *(const f32x4*)(&Om[q * 68 + d0 + 12]);
            bf16x8 o0, o1;
            o0[0] = (__bf16)(s0.x * li); o0[1] = (__bf16)(s0.y * li);
            o0[2] = (__bf16)(s0.z * li); o0[3] = (__bf16)(s0.w * li);
            o0[4] = (__bf16)(s1.x * li); o0[5] = (__bf16)(s1.y * li);
            o0[6] = (__bf16)(s1.z * li); o0[7] = (__bf16)(s1.w * li);
            o1[0] = (__bf16)(s2.x * li); o1[1] = (__bf16)(s2.y * li);
            o1[2] = (__bf16)(s2.z * li); o1[3] = (__bf16)(s2.w * li);
            o1[4] = (__bf16)(s3.x * li); o1[5] = (__bf16)(s3.y * li);
            o1[6] = (__bf16)(s3.z * li); o1[7] = (__bf16)(s3.w * li);
            const int bb = head >> 4, hh = head & 15;
            __bf16* yp = Y + ((size_t)(bb * 2048 + q0w + q)) * 1024 + hh * 64 + d0;
            *(bf16x8*)(yp)     = o0;
            *(bf16x8*)(yp + 8) = o1;
        }
        __syncthreads();
    }
}

// ws layout (bf16 elems), 40 MB total:
// [0,4Mi)     x as bf16 (dead after qkv) -> reused as Y [B,T,C]
// [4Mi,8Mi)   W^T x4 (Wq,Wk,Wv,Wp)
// [8Mi,12Mi)  Q [B,H,T,HD] (pre-scaled)
// [12Mi,16Mi) K [B,H,T,HD]
// [16Mi,20Mi) V^T [B,H,HD,T]  (written directly by qkv_gemm z=2)
#define XB_OFF  0
#define WT_OFF  4194304
#define Q_OFF   8388608
#define K_OFF   12582912
#define VT_OFF  16777216
#define Y_OFF   0

extern "C" void kernel_launch(void* const* d_in, const int* in_sizes, int n_in,
                              void* d_out, int out_size, void* d_ws, size_t ws_size,
                              hipStream_t stream) {
    const float* x  = (const float*)d_in[0];
    const float* Wq = (const float*)d_in[1];
    const float* bq = (const float*)d_in[2];
    const float* Wk = (const float*)d_in[3];
    const float* bk = (const float*)d_in[4];
    const float* Wv = (const float*)d_in[5];
    const float* bv = (const float*)d_in[6];
    const float* Wp = (const float*)d_in[7];
    const float* bp = (const float*)d_in[8];
    __bf16* ws  = (__bf16*)d_ws;
    float*  out = (float*)d_out;
    if (ws_size < (size_t)41943040) return;  // need 40 MB scratch

    prep_kernel<<<dim3(32, 32, 5), dim3(32, 32), 0, stream>>>(x, Wq, Wk, Wv, Wp,
                                                              ws + WT_OFF, ws + XB_OFF);
    qkv_gemm<<<dim3(768), 256, 0, stream>>>(ws + XB_OFF, ws + WT_OFF, bq, bk, bv,
                                            ws + Q_OFF, ws + VT_OFF);
    attn_kernel<<<dim3(256), 512, 0, stream>>>(ws + Q_OFF, ws + K_OFF, ws + VT_OFF,
                                               ws + Y_OFF);
    proj_gemm<<<dim3(512), 256, 0, stream>>>(ws + Y_OFF, ws + WT_OFF + 3 * 1048576, bp, out);
}